// Round 1
// baseline (1783.405 us; speedup 1.0000x reference)
//
#include <hip/hip_runtime.h>

#define EPS 1e-8f

// Kernel A: one thread per face.
// Gather 3 vertices, compute normalized face normal, atomicAdd into acc[N][3].
__global__ void face_normals_kernel(const float* __restrict__ verts,
                                    const int* __restrict__ idx,
                                    float* __restrict__ acc,
                                    int M) {
    int f = blockIdx.x * blockDim.x + threadIdx.x;
    if (f >= M) return;

    int i0 = idx[3 * f + 0];
    int i1 = idx[3 * f + 1];
    int i2 = idx[3 * f + 2];

    float v0x = verts[3 * i0 + 0], v0y = verts[3 * i0 + 1], v0z = verts[3 * i0 + 2];
    float v1x = verts[3 * i1 + 0], v1y = verts[3 * i1 + 1], v1z = verts[3 * i1 + 2];
    float v2x = verts[3 * i2 + 0], v2y = verts[3 * i2 + 1], v2z = verts[3 * i2 + 2];

    float e1x = v1x - v0x, e1y = v1y - v0y, e1z = v1z - v0z;
    float e2x = v2x - v0x, e2y = v2y - v0y, e2z = v2z - v0z;

    float cx = e1y * e2z - e1z * e2y;
    float cy = e1z * e2x - e1x * e2z;
    float cz = e1x * e2y - e1y * e2x;

    float n = sqrtf(cx * cx + cy * cy + cz * cz);
    float inv = 1.0f / fmaxf(n, EPS);
    cx *= inv; cy *= inv; cz *= inv;

    atomicAdd(&acc[3 * i0 + 0], cx);
    atomicAdd(&acc[3 * i0 + 1], cy);
    atomicAdd(&acc[3 * i0 + 2], cz);
    atomicAdd(&acc[3 * i1 + 0], cx);
    atomicAdd(&acc[3 * i1 + 1], cy);
    atomicAdd(&acc[3 * i1 + 2], cz);
    atomicAdd(&acc[3 * i2 + 0], cx);
    atomicAdd(&acc[3 * i2 + 1], cy);
    atomicAdd(&acc[3 * i2 + 2], cz);
}

// Kernel B: one thread per vertex, normalize accumulated normal in place.
__global__ void normalize_kernel(float* __restrict__ out, int N) {
    int v = blockIdx.x * blockDim.x + threadIdx.x;
    if (v >= N) return;

    float x = out[3 * v + 0];
    float y = out[3 * v + 1];
    float z = out[3 * v + 2];
    float n = sqrtf(x * x + y * y + z * z);
    float inv = 1.0f / fmaxf(n, EPS);
    out[3 * v + 0] = x * inv;
    out[3 * v + 1] = y * inv;
    out[3 * v + 2] = z * inv;
}

extern "C" void kernel_launch(void* const* d_in, const int* in_sizes, int n_in,
                              void* d_out, int out_size, void* d_ws, size_t ws_size,
                              hipStream_t stream) {
    const float* verts = (const float*)d_in[0];
    const int* idx = (const int*)d_in[1];
    float* out = (float*)d_out;

    int N = in_sizes[0] / 3;   // 2,000,000 vertices
    int M = in_sizes[1] / 3;   // 4,000,000 faces

    // d_out is poisoned (0xAA) before timing — zero it ourselves each call.
    hipMemsetAsync(d_out, 0, (size_t)out_size * sizeof(float), stream);

    const int BLOCK = 256;
    int gridA = (M + BLOCK - 1) / BLOCK;
    int gridB = (N + BLOCK - 1) / BLOCK;

    face_normals_kernel<<<gridA, BLOCK, 0, stream>>>(verts, idx, out, M);
    normalize_kernel<<<gridB, BLOCK, 0, stream>>>(out, N);
}

// Round 2
// 1782.993 us; speedup vs baseline: 1.0002x; 1.0002x over previous
//
#include <hip/hip_runtime.h>

#define EPS 1e-8f

// Native fp32 atomic add (global_atomic_add_f32): fire-and-forget, no CAS
// loop, no vmcnt dependency. Denorm-flush semantics are acceptable here.
__device__ __forceinline__ void atomic_add_f32_fast(float* p, float v) {
    unsafeAtomicAdd(p, v);
}

// Kernel A: one thread per face.
// Gather 3 vertices, compute normalized face normal, atomic-add into acc[N][3].
__global__ void __launch_bounds__(256)
face_normals_kernel(const float* __restrict__ verts,
                    const int* __restrict__ idx,
                    float* __restrict__ acc,
                    int M) {
    int f = blockIdx.x * blockDim.x + threadIdx.x;
    if (f >= M) return;

    int i0 = idx[3 * f + 0];
    int i1 = idx[3 * f + 1];
    int i2 = idx[3 * f + 2];

    float v0x = verts[3 * i0 + 0], v0y = verts[3 * i0 + 1], v0z = verts[3 * i0 + 2];
    float v1x = verts[3 * i1 + 0], v1y = verts[3 * i1 + 1], v1z = verts[3 * i1 + 2];
    float v2x = verts[3 * i2 + 0], v2y = verts[3 * i2 + 1], v2z = verts[3 * i2 + 2];

    float e1x = v1x - v0x, e1y = v1y - v0y, e1z = v1z - v0z;
    float e2x = v2x - v0x, e2y = v2y - v0y, e2z = v2z - v0z;

    float cx = e1y * e2z - e1z * e2y;
    float cy = e1z * e2x - e1x * e2z;
    float cz = e1x * e2y - e1y * e2x;

    float n = sqrtf(cx * cx + cy * cy + cz * cz);
    float inv = 1.0f / fmaxf(n, EPS);
    cx *= inv; cy *= inv; cz *= inv;

    atomic_add_f32_fast(&acc[3 * i0 + 0], cx);
    atomic_add_f32_fast(&acc[3 * i0 + 1], cy);
    atomic_add_f32_fast(&acc[3 * i0 + 2], cz);
    atomic_add_f32_fast(&acc[3 * i1 + 0], cx);
    atomic_add_f32_fast(&acc[3 * i1 + 1], cy);
    atomic_add_f32_fast(&acc[3 * i1 + 2], cz);
    atomic_add_f32_fast(&acc[3 * i2 + 0], cx);
    atomic_add_f32_fast(&acc[3 * i2 + 1], cy);
    atomic_add_f32_fast(&acc[3 * i2 + 2], cz);
}

// Kernel B: one thread per vertex, normalize accumulated normal in place.
__global__ void __launch_bounds__(256)
normalize_kernel(float* __restrict__ out, int N) {
    int v = blockIdx.x * blockDim.x + threadIdx.x;
    if (v >= N) return;

    float x = out[3 * v + 0];
    float y = out[3 * v + 1];
    float z = out[3 * v + 2];
    float n = sqrtf(x * x + y * y + z * z);
    float inv = 1.0f / fmaxf(n, EPS);
    out[3 * v + 0] = x * inv;
    out[3 * v + 1] = y * inv;
    out[3 * v + 2] = z * inv;
}

extern "C" void kernel_launch(void* const* d_in, const int* in_sizes, int n_in,
                              void* d_out, int out_size, void* d_ws, size_t ws_size,
                              hipStream_t stream) {
    const float* verts = (const float*)d_in[0];
    const int* idx = (const int*)d_in[1];
    float* out = (float*)d_out;

    int N = in_sizes[0] / 3;   // 2,000,000 vertices
    int M = in_sizes[1] / 3;   // 4,000,000 faces

    // d_out is poisoned (0xAA) before timing — zero it ourselves each call.
    hipMemsetAsync(d_out, 0, (size_t)out_size * sizeof(float), stream);

    const int BLOCK = 256;
    int gridA = (M + BLOCK - 1) / BLOCK;
    int gridB = (N + BLOCK - 1) / BLOCK;

    face_normals_kernel<<<gridA, BLOCK, 0, stream>>>(verts, idx, out, M);
    normalize_kernel<<<gridB, BLOCK, 0, stream>>>(out, N);
}

// Round 8
// 1055.155 us; speedup vs baseline: 1.6902x; 1.6898x over previous
//
#include <hip/hip_runtime.h>
#include <hip/hip_cooperative_groups.h>

namespace cg = cooperative_groups;

#define EPS 1e-8f
#define SCALE 16777216.0f            // 2^24 fixed-point scale
#define INV_SCALE (1.0f / 16777216.0f)
#define CHUNK 2500                   // vertices per WG in decode (30 KB LDS)
#define MAX_COOP_WGS 1280            // 5 WG/CU (30KB LDS) * 256 CU

// ---------------- K1: face normals -> packed exact atomics into d_out -----
// xy[v]   : u64 accumulating (Sx*2^24)*2^32 + (Sy*2^24), exact in s64.
// zarr[v] : i32 accumulating Sz*2^24, exact in s32.
__global__ void __launch_bounds__(256)
k1_face_atomics(const float* __restrict__ verts,
                const int* __restrict__ idx,
                unsigned long long* __restrict__ xy,
                int* __restrict__ zarr,
                int M) {
    int f = blockIdx.x * blockDim.x + threadIdx.x;
    if (f >= M) return;

    int i0 = idx[3 * f + 0];
    int i1 = idx[3 * f + 1];
    int i2 = idx[3 * f + 2];

    float v0x = verts[3 * i0 + 0], v0y = verts[3 * i0 + 1], v0z = verts[3 * i0 + 2];
    float v1x = verts[3 * i1 + 0], v1y = verts[3 * i1 + 1], v1z = verts[3 * i1 + 2];
    float v2x = verts[3 * i2 + 0], v2y = verts[3 * i2 + 1], v2z = verts[3 * i2 + 2];

    float e1x = v1x - v0x, e1y = v1y - v0y, e1z = v1z - v0z;
    float e2x = v2x - v0x, e2y = v2y - v0y, e2z = v2z - v0z;

    float cx = e1y * e2z - e1z * e2y;
    float cy = e1z * e2x - e1x * e2z;
    float cz = e1x * e2y - e1y * e2x;

    float n = sqrtf(cx * cx + cy * cy + cz * cz);
    float inv = 1.0f / fmaxf(n, EPS);
    cx *= inv; cy *= inv; cz *= inv;

    long long xs = (long long)__float2int_rn(cx * SCALE);
    long long ys = (long long)__float2int_rn(cy * SCALE);
    int       zs = __float2int_rn(cz * SCALE);
    unsigned long long pk = (unsigned long long)((xs << 32) + ys);

    atomicAdd(&xy[i0], pk);
    atomicAdd(&xy[i1], pk);
    atomicAdd(&xy[i2], pk);
    atomicAdd(&zarr[i0], zs);
    atomicAdd(&zarr[i1], zs);
    atomicAdd(&zarr[i2], zs);
}

// ---------------- K2 (cooperative): decode + normalize + in-place repack --
// Reads packed sums from d_out, decodes into LDS, grid-syncs (all reads
// complete), then writes the final interleaved f32x3 layout over d_out.
// Touches ONLY d_out.
__global__ void __launch_bounds__(256)
k2_decode_normalize(unsigned long long* __restrict__ xy,
                    int* __restrict__ zarr,
                    float* __restrict__ out,
                    int N, int chunk) {
    cg::grid_group grid = cg::this_grid();
    __shared__ __align__(16) float lds[CHUNK * 3];

    int a = blockIdx.x * chunk;
    int b = min(a + chunk, N);

    for (int v = a + (int)threadIdx.x; v < b; v += 256) {
        long long T = (long long)xy[v];
        int sy = (int)(unsigned int)(T & 0xffffffffLL);
        int sx = (int)((T - (long long)sy) >> 32);
        int sz = zarr[v];
        float x = (float)sx * INV_SCALE;
        float y = (float)sy * INV_SCALE;
        float z = (float)sz * INV_SCALE;
        float inv = 1.0f / fmaxf(sqrtf(x * x + y * y + z * z), EPS);
        int l = (v - a) * 3;
        lds[l + 0] = x * inv;
        lds[l + 1] = y * inv;
        lds[l + 2] = z * inv;
    }

    grid.sync();   // every packed read on the whole grid is complete

    int nF = (b - a) * 3;
    int gBase = a * 3;
    // chunk*3 floats; for full chunks (2500*3=7500, base 30000B*k) float4-clean
    if ((nF & 3) == 0 && ((gBase & 3) == 0)) {
        const float4* src = (const float4*)lds;
        float4* dst = (float4*)(out + gBase);
        int n4 = nF >> 2;
        for (int i = threadIdx.x; i < n4; i += 256) dst[i] = src[i];
    } else {
        for (int i = threadIdx.x; i < nF; i += 256) out[gBase + i] = lds[i];
    }
}

// ---------------- fallback (rounds 1-2 proven) ----------------------------
__global__ void __launch_bounds__(256)
face_normals_kernel(const float* __restrict__ verts,
                    const int* __restrict__ idx,
                    float* __restrict__ acc,
                    int M) {
    int f = blockIdx.x * blockDim.x + threadIdx.x;
    if (f >= M) return;
    int i0 = idx[3 * f + 0], i1 = idx[3 * f + 1], i2 = idx[3 * f + 2];
    float v0x = verts[3 * i0], v0y = verts[3 * i0 + 1], v0z = verts[3 * i0 + 2];
    float v1x = verts[3 * i1], v1y = verts[3 * i1 + 1], v1z = verts[3 * i1 + 2];
    float v2x = verts[3 * i2], v2y = verts[3 * i2 + 1], v2z = verts[3 * i2 + 2];
    float e1x = v1x - v0x, e1y = v1y - v0y, e1z = v1z - v0z;
    float e2x = v2x - v0x, e2y = v2y - v0y, e2z = v2z - v0z;
    float cx = e1y * e2z - e1z * e2y;
    float cy = e1z * e2x - e1x * e2z;
    float cz = e1x * e2y - e1y * e2x;
    float n = sqrtf(cx * cx + cy * cy + cz * cz);
    float inv = 1.0f / fmaxf(n, EPS);
    cx *= inv; cy *= inv; cz *= inv;
    atomicAdd(&acc[3 * i0 + 0], cx); atomicAdd(&acc[3 * i0 + 1], cy); atomicAdd(&acc[3 * i0 + 2], cz);
    atomicAdd(&acc[3 * i1 + 0], cx); atomicAdd(&acc[3 * i1 + 1], cy); atomicAdd(&acc[3 * i1 + 2], cz);
    atomicAdd(&acc[3 * i2 + 0], cx); atomicAdd(&acc[3 * i2 + 1], cy); atomicAdd(&acc[3 * i2 + 2], cz);
}

__global__ void __launch_bounds__(256)
normalize_kernel(float* __restrict__ out, int N) {
    int v = blockIdx.x * blockDim.x + threadIdx.x;
    if (v >= N) return;
    float x = out[3 * v], y = out[3 * v + 1], z = out[3 * v + 2];
    float inv = 1.0f / fmaxf(sqrtf(x * x + y * y + z * z), EPS);
    out[3 * v] = x * inv; out[3 * v + 1] = y * inv; out[3 * v + 2] = z * inv;
}

extern "C" void kernel_launch(void* const* d_in, const int* in_sizes, int n_in,
                              void* d_out, int out_size, void* d_ws, size_t ws_size,
                              hipStream_t stream) {
    const float* verts = (const float*)d_in[0];
    const int* idx = (const int*)d_in[1];
    float* out = (float*)d_out;

    int N = in_sizes[0] / 3;   // 2,000,000 vertices
    int M = in_sizes[1] / 3;   // 4,000,000 faces

    const int BLOCK = 256;
    int gridA = (M + BLOCK - 1) / BLOCK;
    int gridB = (N + BLOCK - 1) / BLOCK;

    // packed accumulators live entirely inside d_out:
    //   xy   : u64[N]  at bytes [0, 8N)
    //   zarr : i32[N]  at bytes [8N, 12N)   (12N bytes == out_size*4 exactly)
    unsigned long long* xy = (unsigned long long*)d_out;
    int* zarr = (int*)(out + (size_t)2 * N);

    int coopWGs = (N + CHUNK - 1) / CHUNK;   // 800 for N=2M

    if (coopWGs <= MAX_COOP_WGS && ((size_t)out_size == (size_t)3 * N)) {
        // zero the packed accumulators (whole d_out)
        hipMemsetAsync(d_out, 0, (size_t)out_size * sizeof(float), stream);
        k1_face_atomics<<<gridA, BLOCK, 0, stream>>>(verts, idx, xy, zarr, M);

        int chunk = CHUNK;
        void* args[] = { &xy, &zarr, &out, &N, &chunk };
        hipError_t err = hipLaunchCooperativeKernel((const void*)k2_decode_normalize,
                                                    dim3(coopWGs), dim3(256),
                                                    args, 0, stream);
        if (err == hipSuccess) return;
        // coop launch failed -> redo from scratch with the proven path
    }

    hipMemsetAsync(d_out, 0, (size_t)out_size * sizeof(float), stream);
    face_normals_kernel<<<gridA, BLOCK, 0, stream>>>(verts, idx, out, M);
    normalize_kernel<<<gridB, BLOCK, 0, stream>>>(out, N);
}

// Round 9
// 626.604 us; speedup vs baseline: 2.8461x; 1.6839x over previous
//
#include <hip/hip_runtime.h>
#include <hip/hip_cooperative_groups.h>

namespace cg = cooperative_groups;

#define EPS 1e-8f
#define FSCALE 32768.0f              // 2^15 fixed-point scale per field
#define INV_FSCALE (1.0f / 32768.0f)
#define CHUNK 2500                   // vertices per WG in decode (30 KB LDS)
#define MAX_COOP_WGS 1280

// ---------------- K1: face normals -> ONE packed u64 atomic per corner ----
// acc[v] (u64) accumulates  x*2^42 + y*2^21 + z  (each field: signed fixed
// point, scale 2^15).  Mod-2^64 addition keeps every field's true sum exact;
// the decode below unwinds cross-field borrows exactly.
__global__ void __launch_bounds__(256)
k1_face_atomics(const float* __restrict__ verts,
                const int* __restrict__ idx,
                unsigned long long* __restrict__ acc,
                int M) {
    int f = blockIdx.x * blockDim.x + threadIdx.x;
    if (f >= M) return;

    int i0 = idx[3 * f + 0];
    int i1 = idx[3 * f + 1];
    int i2 = idx[3 * f + 2];

    float v0x = verts[3 * i0 + 0], v0y = verts[3 * i0 + 1], v0z = verts[3 * i0 + 2];
    float v1x = verts[3 * i1 + 0], v1y = verts[3 * i1 + 1], v1z = verts[3 * i1 + 2];
    float v2x = verts[3 * i2 + 0], v2y = verts[3 * i2 + 1], v2z = verts[3 * i2 + 2];

    float e1x = v1x - v0x, e1y = v1y - v0y, e1z = v1z - v0z;
    float e2x = v2x - v0x, e2y = v2y - v0y, e2z = v2z - v0z;

    float cx = e1y * e2z - e1z * e2y;
    float cy = e1z * e2x - e1x * e2z;
    float cz = e1x * e2y - e1y * e2x;

    float n = sqrtf(cx * cx + cy * cy + cz * cz);
    float inv = 1.0f / fmaxf(n, EPS);

    long long xs = (long long)__float2int_rn(cx * inv * FSCALE);
    long long ys = (long long)__float2int_rn(cy * inv * FSCALE);
    long long zs = (long long)__float2int_rn(cz * inv * FSCALE);

    unsigned long long pk = ((unsigned long long)xs << 42)
                          + ((unsigned long long)ys << 21)
                          +  (unsigned long long)zs;

    atomicAdd(&acc[i0], pk);
    atomicAdd(&acc[i1], pk);
    atomicAdd(&acc[i2], pk);
}

// ---------------- K2 (cooperative): decode + normalize + in-place repack --
// acc overlaps out (bytes [0,16MB) of d_out). Decode everything this WG owns
// into LDS, grid.sync (ALL reads done grid-wide), then write final floats.
__global__ void __launch_bounds__(256)
k2_decode_normalize(unsigned long long* __restrict__ acc,
                    float* __restrict__ out,
                    int N, int chunk) {
    cg::grid_group grid = cg::this_grid();
    __shared__ __align__(16) float lds[CHUNK * 3];

    int a = blockIdx.x * chunk;
    int b = min(a + chunk, N);

    for (int v = a + (int)threadIdx.x; v < b; v += 256) {
        unsigned long long T = acc[v];
        // exact 3-field decode (borrow-cancelling)
        long long C = ((long long)(T << 43)) >> 43;          // low 21 bits, sext
        unsigned long long T1 = T - (unsigned long long)C;
        long long B = ((long long)(T1 << 22)) >> 43;         // bits 21..41, sext
        unsigned long long T2 = T1 - ((unsigned long long)B << 21);
        long long A = ((long long)T2) >> 42;                 // top 22 bits, sext

        float x = (float)A * INV_FSCALE;
        float y = (float)B * INV_FSCALE;
        float z = (float)C * INV_FSCALE;
        float inv = 1.0f / fmaxf(sqrtf(x * x + y * y + z * z), EPS);
        int l = (v - a) * 3;
        lds[l + 0] = x * inv;
        lds[l + 1] = y * inv;
        lds[l + 2] = z * inv;
    }

    grid.sync();   // every acc[] read on the whole grid is complete

    int nF = (b - a) * 3;
    int gBase = a * 3;
    if ((nF & 3) == 0) {
        const float4* src = (const float4*)lds;
        float4* dst = (float4*)(out + gBase);   // gBase*4 = 30000*blk, 16B-aligned
        int n4 = nF >> 2;
        for (int i = threadIdx.x; i < n4; i += 256) dst[i] = src[i];
    } else {
        for (int i = threadIdx.x; i < nF; i += 256) out[gBase + i] = lds[i];
    }
}

// ---------------- fallback (rounds 1-2 proven) ----------------------------
__global__ void __launch_bounds__(256)
face_normals_kernel(const float* __restrict__ verts,
                    const int* __restrict__ idx,
                    float* __restrict__ acc,
                    int M) {
    int f = blockIdx.x * blockDim.x + threadIdx.x;
    if (f >= M) return;
    int i0 = idx[3 * f + 0], i1 = idx[3 * f + 1], i2 = idx[3 * f + 2];
    float v0x = verts[3 * i0], v0y = verts[3 * i0 + 1], v0z = verts[3 * i0 + 2];
    float v1x = verts[3 * i1], v1y = verts[3 * i1 + 1], v1z = verts[3 * i1 + 2];
    float v2x = verts[3 * i2], v2y = verts[3 * i2 + 1], v2z = verts[3 * i2 + 2];
    float e1x = v1x - v0x, e1y = v1y - v0y, e1z = v1z - v0z;
    float e2x = v2x - v0x, e2y = v2y - v0y, e2z = v2z - v0z;
    float cx = e1y * e2z - e1z * e2y;
    float cy = e1z * e2x - e1x * e2z;
    float cz = e1x * e2y - e1y * e2x;
    float n = sqrtf(cx * cx + cy * cy + cz * cz);
    float inv = 1.0f / fmaxf(n, EPS);
    cx *= inv; cy *= inv; cz *= inv;
    atomicAdd(&acc[3 * i0 + 0], cx); atomicAdd(&acc[3 * i0 + 1], cy); atomicAdd(&acc[3 * i0 + 2], cz);
    atomicAdd(&acc[3 * i1 + 0], cx); atomicAdd(&acc[3 * i1 + 1], cy); atomicAdd(&acc[3 * i1 + 2], cz);
    atomicAdd(&acc[3 * i2 + 0], cx); atomicAdd(&acc[3 * i2 + 1], cy); atomicAdd(&acc[3 * i2 + 2], cz);
}

__global__ void __launch_bounds__(256)
normalize_kernel(float* __restrict__ out, int N) {
    int v = blockIdx.x * blockDim.x + threadIdx.x;
    if (v >= N) return;
    float x = out[3 * v], y = out[3 * v + 1], z = out[3 * v + 2];
    float inv = 1.0f / fmaxf(sqrtf(x * x + y * y + z * z), EPS);
    out[3 * v] = x * inv; out[3 * v + 1] = y * inv; out[3 * v + 2] = z * inv;
}

extern "C" void kernel_launch(void* const* d_in, const int* in_sizes, int n_in,
                              void* d_out, int out_size, void* d_ws, size_t ws_size,
                              hipStream_t stream) {
    const float* verts = (const float*)d_in[0];
    const int* idx = (const int*)d_in[1];
    float* out = (float*)d_out;

    int N = in_sizes[0] / 3;   // 2,000,000 vertices
    int M = in_sizes[1] / 3;   // 4,000,000 faces

    const int BLOCK = 256;
    int gridA = (M + BLOCK - 1) / BLOCK;
    int gridB = (N + BLOCK - 1) / BLOCK;

    // packed accumulator: u64[N] at d_out bytes [0, 8N)  (8N <= 12N = out bytes)
    unsigned long long* acc = (unsigned long long*)d_out;
    int coopWGs = (N + CHUNK - 1) / CHUNK;   // 800 for N=2M

    if (coopWGs <= MAX_COOP_WGS && ((size_t)out_size == (size_t)3 * N)) {
        hipMemsetAsync(d_out, 0, (size_t)N * sizeof(unsigned long long), stream);
        k1_face_atomics<<<gridA, BLOCK, 0, stream>>>(verts, idx, acc, M);

        int chunk = CHUNK;
        void* args[] = { &acc, &out, &N, &chunk };
        hipError_t err = hipLaunchCooperativeKernel((const void*)k2_decode_normalize,
                                                    dim3(coopWGs), dim3(256),
                                                    args, 0, stream);
        if (err == hipSuccess) return;
        // coop launch failed -> redo from scratch with the proven path
    }

    hipMemsetAsync(d_out, 0, (size_t)out_size * sizeof(float), stream);
    face_normals_kernel<<<gridA, BLOCK, 0, stream>>>(verts, idx, out, M);
    normalize_kernel<<<gridB, BLOCK, 0, stream>>>(out, N);
}